// Round 12
// baseline (311.707 us; speedup 1.0000x reference)
//
#include <hip/hip_runtime.h>

#define DEVINL __device__ __forceinline__

typedef __attribute__((ext_vector_type(8))) short short8;
typedef __attribute__((ext_vector_type(4))) short sh4;
typedef __attribute__((ext_vector_type(4))) float floatx4;

constexpr int S_LEN = 2048;
constexpr int DM    = 1024;
constexpr int NHEAD = 16;
constexpr int DHEAD = 64;
constexpr int BATCH = 2;
constexpr int MROWS = BATCH * S_LEN; // 4096
constexpr float LOG2E = 1.44269504f;
// fixed-max softmax: p = exp2(s_raw*0.125*LOG2E - 24*LOG2E); normalization cancels in O/l.
constexpr float SM_C1 = 0.125f * LOG2E;
constexpr float SM_C2 = -24.0f * LOG2E;

// 16x16x16 bf16 MFMA (A/B = 4 bf16 = 2 VGPR). No __has_builtin guard — amdgcn
// builtins are aux-target in the host pass (guard returns false there).
#define MFMA16(a, b, c) __builtin_amdgcn_mfma_f32_16x16x16bf16_1k(a, b, c, 0, 0, 0)

DEVINL unsigned short f2bf(float x) {  // RNE
  union { float f; unsigned u; } un; un.f = x;
  unsigned u = un.u;
  return (unsigned short)((u + 0x7fffu + ((u >> 16) & 1u)) >> 16);
}
DEVINL unsigned short f2bf_fast(float x) {  // round-half-up (x >= 0)
  union { float f; unsigned u; } un; un.f = x;
  return (unsigned short)((un.u + 0x8000u) >> 16);
}

// ---------------- prep: fp32->bf16 convert (3 tensors) + weight transpose (4) ----------------
__global__ __launch_bounds__(256) void prep_kernel(const float* __restrict__ s0,
                                                   const float* __restrict__ s1,
                                                   const float* __restrict__ s2,
                                                   unsigned short* __restrict__ d0,
                                                   unsigned short* __restrict__ d1,
                                                   unsigned short* __restrict__ d2,
                                                   const float* __restrict__ W0,
                                                   const float* __restrict__ W1,
                                                   const float* __restrict__ W2,
                                                   const float* __restrict__ W3,
                                                   unsigned short* __restrict__ T0,
                                                   unsigned short* __restrict__ T1,
                                                   unsigned short* __restrict__ T2,
                                                   unsigned short* __restrict__ T3) {
  __shared__ unsigned short tile[32][33];
  const int y = blockIdx.y;
  if (y < 3) {
    const float* s = y == 0 ? s0 : (y == 1 ? s1 : s2);
    unsigned short* d = y == 0 ? d0 : (y == 1 ? d1 : d2);
    int i = (blockIdx.x * 256 + threadIdx.x) * 4;
    float4 v = *(const float4*)(s + i);
    unsigned lo = (unsigned)f2bf(v.x) | ((unsigned)f2bf(v.y) << 16);
    unsigned hi = (unsigned)f2bf(v.z) | ((unsigned)f2bf(v.w) << 16);
    *(uint2*)(d + i) = make_uint2(lo, hi);
  } else {
    const int x = blockIdx.x;
    const int wsel = x >> 10, rem = x & 1023;
    const float* W = wsel == 0 ? W0 : (wsel == 1 ? W1 : (wsel == 2 ? W2 : W3));
    unsigned short* Wt = wsel == 0 ? T0 : (wsel == 1 ? T1 : (wsel == 2 ? T2 : T3));
    int t = threadIdx.x;
    int c = t & 31, r0 = t >> 5;
    int nB = (rem & 31) * 32, kB = (rem >> 5) * 32;
    for (int i = 0; i < 4; ++i) {
      int r = r0 + i * 8;
      tile[r][c] = f2bf(W[(size_t)(kB + r) * DM + nB + c]);
    }
    __syncthreads();
    for (int i = 0; i < 4; ++i) {
      int r = r0 + i * 8;
      Wt[(size_t)(nB + r) * DM + kB + c] = tile[c][r];
    }
  }
}

// ------------- async 16B global->LDS -------------
DEVINL void load_lds16(const unsigned short* g, unsigned short* l) {
  __builtin_amdgcn_global_load_lds((const __attribute__((address_space(1))) unsigned int*)g,
                                   (__attribute__((address_space(3))) unsigned int*)l,
                                   16, 0, 0);
}

// ------------- GEMM body (128x128 tile): C = A[4096][1024] @ Bt^T -------------
// MODE 0: bf16 row-major out; MODE 2: bf16 V-transposed out
// (vt[(b*16+h)*64+d][s], fusing the V-transpose into the V projection).
template <int MODE>
DEVINL void gemm_body(const unsigned short* __restrict__ A,
                      const unsigned short* __restrict__ Bt,
                      void* __restrict__ Cout) {
  constexpr int K = 1024, N = 1024;
  __shared__ alignas(16) unsigned short As[128 * 32];
  __shared__ alignas(16) unsigned short Bs[128 * 32];
  const int tid  = threadIdx.x;
  const int wave = tid >> 6, lane = tid & 63;
  const int quad = lane >> 4, l16 = lane & 15;
  const int mBase = blockIdx.y * 128, nBase = blockIdx.x * 128;
  const int wm = (wave >> 1) * 64, wn = (wave & 1) * 64;
  const int sr = lane >> 2;
  const int sc = (lane & 3) * 8;
  floatx4 acc[4][4] = {};

  for (int k0 = 0; k0 < K; k0 += 32) {
    __syncthreads();
#pragma unroll
    for (int j = 0; j < 2; ++j) {
      int row = wave * 32 + j * 16 + sr;
      load_lds16(A  + (size_t)(mBase + row) * K + k0 + sc, As + (wave * 32 + j * 16) * 32);
      load_lds16(Bt + (size_t)(nBase + row) * K + k0 + sc, Bs + (wave * 32 + j * 16) * 32);
    }
    __syncthreads();
    short8 af[4], bfr[4];
#pragma unroll
    for (int mt = 0; mt < 4; ++mt) af[mt]  = *(const short8*)&As[(wm + mt * 16 + l16) * 32 + quad * 8];
#pragma unroll
    for (int nt = 0; nt < 4; ++nt) bfr[nt] = *(const short8*)&Bs[(wn + nt * 16 + l16) * 32 + quad * 8];
#pragma unroll
    for (int mt = 0; mt < 4; ++mt)
#pragma unroll
      for (int nt = 0; nt < 4; ++nt)
        acc[mt][nt] = __builtin_amdgcn_mfma_f32_16x16x32_bf16(af[mt], bfr[nt], acc[mt][nt], 0, 0, 0);
  }

#pragma unroll
  for (int mt = 0; mt < 4; ++mt)
#pragma unroll
    for (int nt = 0; nt < 4; ++nt) {
      const int m = mBase + wm + mt * 16 + quad * 4;   // +r
      const int n = nBase + wn + nt * 16 + l16;
      if (MODE == 2) {
        const int bq = m >> 11, s = m & 2047;
        const int hh = n >> 6,  d = n & 63;
        unsigned short w4[4];
#pragma unroll
        for (int r = 0; r < 4; ++r) w4[r] = f2bf(acc[mt][nt][r]);
        *(uint2*)&((unsigned short*)Cout)[((size_t)((bq * 16 + hh) * 64 + d)) * S_LEN + s] =
            *(const uint2*)w4;
      } else {
#pragma unroll
        for (int r = 0; r < 4; ++r)
          ((unsigned short*)Cout)[(size_t)(m + r) * N + n] = f2bf(acc[mt][nt][r]);
      }
    }
}

__global__ __launch_bounds__(256) void gemm_qkv(const unsigned short* __restrict__ A0,
                                                const unsigned short* __restrict__ A1,
                                                const unsigned short* __restrict__ A2,
                                                const unsigned short* __restrict__ B0,
                                                const unsigned short* __restrict__ B1,
                                                const unsigned short* __restrict__ B2,
                                                unsigned short* __restrict__ C0,
                                                unsigned short* __restrict__ C1,
                                                unsigned short* __restrict__ C2) {
  const int z = blockIdx.z;
  if (z == 2)      gemm_body<2>(A2, B2, C2);   // V: write transposed vt directly
  else if (z == 1) gemm_body<0>(A1, B1, C1);
  else             gemm_body<0>(A0, B0, C0);
}

// ------------- output GEMM, 64x128 tile (512 blocks -> 2/CU overlap) -------------
__global__ __launch_bounds__(256) void gemm_out64(const unsigned short* __restrict__ A,
                                                  const unsigned short* __restrict__ Bt,
                                                  float* __restrict__ C) {
  constexpr int K = 1024, N = 1024;
  __shared__ alignas(16) unsigned short As[64 * 32];
  __shared__ alignas(16) unsigned short Bs[128 * 32];
  const int tid  = threadIdx.x;
  const int wave = tid >> 6, lane = tid & 63;
  const int quad = lane >> 4, l16 = lane & 15;
  const int mBase = blockIdx.y * 64, nBase = blockIdx.x * 128;
  const int wm = (wave >> 1) * 32, wn = (wave & 1) * 64;
  const int sr = lane >> 2;
  const int sc = (lane & 3) * 8;
  floatx4 acc[2][4] = {};

  for (int k0 = 0; k0 < K; k0 += 32) {
    __syncthreads();
    load_lds16(A + (size_t)(mBase + wave * 16 + sr) * K + k0 + sc, As + (wave * 16) * 32);
#pragma unroll
    for (int j = 0; j < 2; ++j) {
      int row = wave * 32 + j * 16 + sr;
      load_lds16(Bt + (size_t)(nBase + row) * K + k0 + sc, Bs + (wave * 32 + j * 16) * 32);
    }
    __syncthreads();
    short8 af[2], bfr[4];
#pragma unroll
    for (int mt = 0; mt < 2; ++mt) af[mt]  = *(const short8*)&As[(wm + mt * 16 + l16) * 32 + quad * 8];
#pragma unroll
    for (int nt = 0; nt < 4; ++nt) bfr[nt] = *(const short8*)&Bs[(wn + nt * 16 + l16) * 32 + quad * 8];
#pragma unroll
    for (int mt = 0; mt < 2; ++mt)
#pragma unroll
      for (int nt = 0; nt < 4; ++nt)
        acc[mt][nt] = __builtin_amdgcn_mfma_f32_16x16x32_bf16(af[mt], bfr[nt], acc[mt][nt], 0, 0, 0);
  }

#pragma unroll
  for (int mt = 0; mt < 2; ++mt)
#pragma unroll
    for (int nt = 0; nt < 4; ++nt)
#pragma unroll
      for (int r = 0; r < 4; ++r) {
        int m = mBase + wm + mt * 16 + quad * 4 + r;
        int n = nBase + wn + nt * 16 + l16;
        C[(size_t)m * N + n] = acc[mt][nt][r];
      }
}

// ------------- causal flash attention: triple-buffered K/V, counted vmcnt, register P ----
// S^T trick: QK as A=K,B=Q -> lane holds P[q=l16][s=quad*4+r] = A-operand layout of
// mfma 16x16x16 for PV -> P never leaves registers.
//
// R20 (this round): COUNTED-VMCNT 2-DEEP PIPELINE (T4) on the R16 base (45.4us).
// R16's step = ~1650 cyc vs ~650 cyc of real work: the 1-deep prefetch drained
// vmcnt(0) every step (both our asm and hipcc's own drain before __syncthreads),
// exposing DMA completion (L2 line contention: 16 lockstep blocks re-read the
// same tile lines). Fix per the m97->m218 ladder: NEVER drain to 0 in-loop —
//   * triple-buffered K/V (3 x 16 KB), continuous 2-ahead issue stream (tile
//     g+2 issued at step g; stream crosses the half boundary; dummy-issue of
//     tile 0 past stream end keeps the vmcnt count invariant).
//   * per step: s_waitcnt vmcnt(4)  (4 loads/tile/thread; waits ONLY the 4
//     oldest = tile t) -> raw __builtin_amdgcn_s_barrier() (no implicit full
//     drain, unlike __syncthreads) fenced with sched_barrier(0) so reads can't
//     hoist above the barrier and the DMA issues can't cross the waitcnt.
//   * DMA now has ~2 compute phases to complete -> drain ~free.
// Epilogue: 5 KB shared-atomicAdd accumulator (R19-proven) so 3 buffers fit in
// 64 KB static LDS (55,296 B). FULLY-UNROLLED nt loop (rule #20: runtime
// indexing of o[] forces the accumulators to scratch — R15/R17/R18 all hit
// 400MB-1GB scratch writes from one `#pragma unroll 1`).
// R19 lesson: q-split reverted (125us: doubles staging, halves per-block
// compute, 32 lockstep blocks/XCD hot-line the same K/V tile).
// R16: XCD remap — all 16 pair-blocks of a bh on one XCD, K/V L2-resident
// (FETCH 96->12 MB). R13: explicit waitcnt discipline (R12 raced without it).
// XOR swizzle chunk^=(row&7) both-sides. R9: pair (31-p, p) => uniform 33 steps.
__global__ __launch_bounds__(256, 3) void attn_kernel(const unsigned short* __restrict__ Qp,
                                                      const unsigned short* __restrict__ Kp,
                                                      const unsigned short* __restrict__ Vtg,
                                                      unsigned short* __restrict__ ctx) {
  // ---- XCD-aware remap: keep all 16 pair-blocks of a bh on one XCD ----
  const int lin = (int)blockIdx.y * 16 + (int)blockIdx.x;   // dispatch linear id
  const int xcd = lin & 7;
  const int kk  = lin >> 3;                // 0..63
  const int bh  = ((kk >> 4) << 3) | xcd;  // 4 bh per XCD
  const int pairIdx = kk & 15;
  const int b  = bh >> 4, h = bh & 15;
  const int tid = threadIdx.x;
  const int w = tid >> 6, lane = tid & 63;
  const int quad = lane >> 4, l16 = lane & 15;

  // separate typed LDS (no aliasing). 49152 + 5120 + 1024 = 55296 B.
  __shared__ alignas(16) unsigned short KVs[3 * 8192];  // 3 buffers x (K 4096 | V 4096)
  __shared__ alignas(16) float Acc[4][16][20];          // atomic merge [dt][d16][q16 pad]
  __shared__ float rsL[4][4][16];                       // [wave][nt][q16]

  const unsigned short* Kbh = Kp  + (size_t)(b * S_LEN) * DM + h * DHEAD;
  const unsigned short* Vbh = Vtg + (size_t)(bh * DHEAD) * S_LEN;

  // ---- DMA staging geometry: wave w stages segment w*4KB of the 16KB tile pair ----
  int srow[4], scol[4];
#pragma unroll
  for (int j = 0; j < 4; ++j) {
    const int p = (w & 1) * 256 + j * 64 + lane;
    srow[j] = p >> 3;
    scol[j] = ((p & 7) ^ (srow[j] & 7)) * 8;
  }
  const bool stageK = (w < 2);

  // ---- swizzled read addresses (within a buffer, shorts) ----
  const int swz = l16 & 7;
  const int kRow = (w * 16 + l16) * 64;
  const int kOff0 = kRow + ((0 + quad) ^ swz) * 8;       // K chunks quad, 4+quad
  const int kOff1 = kRow + ((4 + quad) ^ swz) * 8;
  int vOff[4];
#pragma unroll
  for (int dt = 0; dt < 4; ++dt) {
    const int ch = 2 * w + (quad >> 1);
    vOff[dt] = 4096 + (dt * 16 + l16) * 64 + (ch ^ swz) * 8 + (quad & 1) * 4;
  }

  const int nT0 = 32 - pairIdx;   // first (heavy) q-tile steps
  const int nT1 = pairIdx + 1;    // second q-tile steps

  // global tile stream: g<nT0 -> tile g; else tile g-nT0 of half 1; else dummy 0
  auto kbOf = [&](int g) -> int {
    if (g < nT0) return g * 64;
    const int gg = g - nT0;
    return (gg < nT1) ? gg * 64 : 0;
  };
  auto issueTile = [&](int kb, int wbuf) {
    unsigned short* dst = KVs + wbuf * 8192 + w * 2048;
#pragma unroll
    for (int j = 0; j < 4; ++j) {
      const unsigned short* src = stageK
          ? Kbh + (size_t)(kb + srow[j]) * DM + scol[j]
          : Vbh + (size_t)srow[j] * S_LEN + kb + scol[j];
      load_lds16(src, dst + j * 512);
    }
  };

  // prologue: 2-deep prefetch (8 outstanding loads/thread)
  issueTile(kbOf(0), 0);
  issueTile(kbOf(1), 1);
  int rb = 0, wb = 2, g = 0;

#pragma unroll 1
  for (int half = 0; half < 2; ++half) {
    const int qt = half ? pairIdx : 31 - pairIdx;  // heavy tile first
    const int Q0 = qt * 64;
    const int nT = half ? nT1 : nT0;

    // Q fragments (B-operand: n=l16 -> q, k=quad*8+j -> d)
    short8 qB[4][2];
#pragma unroll
    for (int nt = 0; nt < 4; ++nt) {
      const size_t qr = ((size_t)(b * S_LEN + Q0 + nt * 16 + l16)) * DM + h * DHEAD + quad * 8;
      qB[nt][0] = *(const short8*)&Qp[qr];
      qB[nt][1] = *(const short8*)&Qp[qr + 32];
    }

    floatx4 o[4][4] = {};
    float rs[4] = {0.f, 0.f, 0.f, 0.f};

#pragma unroll 1
    for (int t = 0; t < nT; ++t) {
      // counted drain: wait ONLY the 4 oldest loads (tile t). Raw barrier
      // (no hipcc vmcnt(0)). sched_barrier pins: DMA issues can't hoist above
      // the waitcnt; LDS reads can't hoist above the barrier.
      asm volatile("s_waitcnt vmcnt(4)" ::: "memory");
      __builtin_amdgcn_sched_barrier(0);
      __builtin_amdgcn_s_barrier();
      __builtin_amdgcn_sched_barrier(0);

      // fragments from LDS (swizzled), current buffer rb
      const unsigned short* buf = KVs + rb * 8192;
      short8 kc0 = *(const short8*)&buf[kOff0];
      short8 kc1 = *(const short8*)&buf[kOff1];
      sh4 vv[4];
#pragma unroll
      for (int dt = 0; dt < 4; ++dt) vv[dt] = *(const sh4*)&buf[vOff[dt]];

      // issue tile g+2 into wb (always: dummy tile 0 past stream end keeps
      // the vmcnt invariant at 8 outstanding)
      issueTile(kbOf(g + 2), wb);

      const bool masked = (t == nT - 1);
      const int sbase = w * 16 + quad * 4;   // s - kb, + r

#pragma unroll
      for (int nt = 0; nt < 4; ++nt) {
        floatx4 sc = {};
        sc = __builtin_amdgcn_mfma_f32_16x16x32_bf16(kc0, qB[nt][0], sc, 0, 0, 0);
        sc = __builtin_amdgcn_mfma_f32_16x16x32_bf16(kc1, qB[nt][1], sc, 0, 0, 0);
        const int qoff = nt * 16 + l16;      // q - Q0
        sh4 pa;
        float acc = 0.f;
#pragma unroll
        for (int r = 0; r < 4; ++r) {
          float p = __builtin_amdgcn_exp2f(fmaf(sc[r], SM_C1, SM_C2));
          if (masked && (sbase + r > qoff)) p = 0.f;
          acc += p;
          pa[r] = (short)f2bf_fast(p);
        }
        rs[nt] += acc;
#pragma unroll
        for (int dt = 0; dt < 4; ++dt)
          o[nt][dt] = MFMA16(pa, vv[dt], o[nt][dt]);
      }

      rb = (rb == 2) ? 0 : rb + 1;
      wb = (wb == 2) ? 0 : wb + 1;
      ++g;
    }

    // ---- epilogue: atomic merge of 4 wave-partials, normalize, write ctx ----
    // __syncthreads here drains the in-flight prewarm DMAs once per half (its
    // implicit vmcnt(0)) — data then sits ready in LDS for the next half.
#pragma unroll
    for (int nt = 0; nt < 4; ++nt) {
      rs[nt] += __shfl_xor(rs[nt], 16, 64);
      rs[nt] += __shfl_xor(rs[nt], 32, 64);
    }
    if (quad == 0) {
#pragma unroll
      for (int nt = 0; nt < 4; ++nt) rsL[w][nt][l16] = rs[nt];
    }

#pragma unroll
    for (int nt = 0; nt < 4; ++nt) {
      __syncthreads();                       // Acc free (prev round read done)
      {  // cooperative zero: 1280 floats / 256 threads = 5 each
        float* af = &Acc[0][0][0];
#pragma unroll
        for (int z = 0; z < 5; ++z) af[tid * 5 + z] = 0.f;
      }
      __syncthreads();
#pragma unroll
      for (int dt = 0; dt < 4; ++dt)
#pragma unroll
        for (int j = 0; j < 4; ++j)
          atomicAdd(&Acc[dt][l16][quad * 4 + j], o[nt][dt][j]);
      __syncthreads();
      // wave w outputs d-tile dt == w; lane -> (q16 = quad*4+j, d16 = l16)
#pragma unroll
      for (int j = 0; j < 4; ++j) {
        const int q16 = quad * 4 + j;
        const float l = rsL[0][nt][q16] + rsL[1][nt][q16] +
                        rsL[2][nt][q16] + rsL[3][nt][q16];
        const size_t row = (size_t)(b * S_LEN + Q0 + nt * 16 + q16);
        ctx[row * DM + h * DHEAD + w * 16 + l16] = f2bf(Acc[w][l16][q16] / l);
      }
    }
  }
}

extern "C" void kernel_launch(void* const* d_in, const int* in_sizes, int n_in,
                              void* d_out, int out_size, void* d_ws, size_t ws_size,
                              hipStream_t stream) {
  const float* Xq = (const float*)d_in[0];
  const float* Xk = (const float*)d_in[1];
  const float* Xv = (const float*)d_in[2];
  const float* Wq = (const float*)d_in[5];
  const float* Wk = (const float*)d_in[6];
  const float* Wv = (const float*)d_in[7];
  const float* Wo = (const float*)d_in[8];
  float* out = (float*)d_out;

  char* ws = (char*)d_ws;
  constexpr size_t XBYTES = (size_t)MROWS * DM * 2;  // 8 MiB
  constexpr size_t WBYTES = (size_t)DM * DM * 2;     // 2 MiB
  unsigned short* xq_bf = (unsigned short*)(ws);
  unsigned short* xk_bf = (unsigned short*)(ws + XBYTES);
  unsigned short* xv_bf = (unsigned short*)(ws + 2 * XBYTES);
  unsigned short* wqt   = (unsigned short*)(ws + 3 * XBYTES);
  unsigned short* wkt   = (unsigned short*)(ws + 3 * XBYTES + WBYTES);
  unsigned short* wvt   = (unsigned short*)(ws + 3 * XBYTES + 2 * WBYTES);
  unsigned short* wot   = (unsigned short*)(ws + 3 * XBYTES + 3 * WBYTES);
  unsigned short* qp    = (unsigned short*)(ws + 3 * XBYTES + 4 * WBYTES);
  unsigned short* kp    = (unsigned short*)(ws + 4 * XBYTES + 4 * WBYTES);
  unsigned short* vt    = (unsigned short*)(ws + 5 * XBYTES + 4 * WBYTES); // V^T, written by V-GEMM
  unsigned short* ctx   = xq_bf;  // dead after Q projection

  // fused prep: y=0..2 convert Xq/Xk/Xv; y=3 transpose the 4 weights
  prep_kernel<<<dim3(4096, 4), 256, 0, stream>>>(Xq, Xk, Xv, xq_bf, xk_bf, xv_bf,
                                                 Wq, Wk, Wv, Wo, wqt, wkt, wvt, wot);

  gemm_qkv<<<dim3(DM / 128, MROWS / 128, 3), 256, 0, stream>>>(
      xq_bf, xk_bf, xv_bf, wqt, wkt, wvt, qp, kp, vt);

  // paired causal schedule + XCD remap: block lin -> (bh with bh%8==lin%8, pair)
  // => all 16 pair-blocks of a bh on one XCD; uniform 33 steps each; 512 blocks.
  attn_kernel<<<dim3(16, BATCH * NHEAD), 256, 0, stream>>>(qp, kp, vt, ctx);

  gemm_out64<<<dim3(DM / 128, MROWS / 64), 256, 0, stream>>>(ctx, wot, out);
}

// Round 13
// 305.398 us; speedup vs baseline: 1.0207x; 1.0207x over previous
//
#include <hip/hip_runtime.h>

#define DEVINL __device__ __forceinline__

typedef __attribute__((ext_vector_type(8))) short short8;
typedef __attribute__((ext_vector_type(4))) short sh4;
typedef __attribute__((ext_vector_type(4))) float floatx4;

constexpr int S_LEN = 2048;
constexpr int DM    = 1024;
constexpr int NHEAD = 16;
constexpr int DHEAD = 64;
constexpr int BATCH = 2;
constexpr int MROWS = BATCH * S_LEN; // 4096
constexpr float LOG2E = 1.44269504f;
// fixed-max softmax: p = exp2(s_raw*0.125*LOG2E - 24*LOG2E); normalization cancels in O/l.
constexpr float SM_C1 = 0.125f * LOG2E;
constexpr float SM_C2 = -24.0f * LOG2E;

// 16x16x16 bf16 MFMA (A/B = 4 bf16 = 2 VGPR). No __has_builtin guard — amdgcn
// builtins are aux-target in the host pass (guard returns false there).
#define MFMA16(a, b, c) __builtin_amdgcn_mfma_f32_16x16x16bf16_1k(a, b, c, 0, 0, 0)

DEVINL unsigned short f2bf(float x) {  // RNE
  union { float f; unsigned u; } un; un.f = x;
  unsigned u = un.u;
  return (unsigned short)((u + 0x7fffu + ((u >> 16) & 1u)) >> 16);
}
DEVINL unsigned short f2bf_fast(float x) {  // round-half-up (x >= 0)
  union { float f; unsigned u; } un; un.f = x;
  return (unsigned short)((un.u + 0x8000u) >> 16);
}

// ---------------- prep: fp32->bf16 convert (3 tensors) + weight transpose (4) ----------------
__global__ __launch_bounds__(256) void prep_kernel(const float* __restrict__ s0,
                                                   const float* __restrict__ s1,
                                                   const float* __restrict__ s2,
                                                   unsigned short* __restrict__ d0,
                                                   unsigned short* __restrict__ d1,
                                                   unsigned short* __restrict__ d2,
                                                   const float* __restrict__ W0,
                                                   const float* __restrict__ W1,
                                                   const float* __restrict__ W2,
                                                   const float* __restrict__ W3,
                                                   unsigned short* __restrict__ T0,
                                                   unsigned short* __restrict__ T1,
                                                   unsigned short* __restrict__ T2,
                                                   unsigned short* __restrict__ T3) {
  __shared__ unsigned short tile[32][33];
  const int y = blockIdx.y;
  if (y < 3) {
    const float* s = y == 0 ? s0 : (y == 1 ? s1 : s2);
    unsigned short* d = y == 0 ? d0 : (y == 1 ? d1 : d2);
    int i = (blockIdx.x * 256 + threadIdx.x) * 4;
    float4 v = *(const float4*)(s + i);
    unsigned lo = (unsigned)f2bf(v.x) | ((unsigned)f2bf(v.y) << 16);
    unsigned hi = (unsigned)f2bf(v.z) | ((unsigned)f2bf(v.w) << 16);
    *(uint2*)(d + i) = make_uint2(lo, hi);
  } else {
    const int x = blockIdx.x;
    const int wsel = x >> 10, rem = x & 1023;
    const float* W = wsel == 0 ? W0 : (wsel == 1 ? W1 : (wsel == 2 ? W2 : W3));
    unsigned short* Wt = wsel == 0 ? T0 : (wsel == 1 ? T1 : (wsel == 2 ? T2 : T3));
    int t = threadIdx.x;
    int c = t & 31, r0 = t >> 5;
    int nB = (rem & 31) * 32, kB = (rem >> 5) * 32;
    for (int i = 0; i < 4; ++i) {
      int r = r0 + i * 8;
      tile[r][c] = f2bf(W[(size_t)(kB + r) * DM + nB + c]);
    }
    __syncthreads();
    for (int i = 0; i < 4; ++i) {
      int r = r0 + i * 8;
      Wt[(size_t)(nB + r) * DM + kB + c] = tile[c][r];
    }
  }
}

// ------------- async 16B global->LDS -------------
DEVINL void load_lds16(const unsigned short* g, unsigned short* l) {
  __builtin_amdgcn_global_load_lds((const __attribute__((address_space(1))) unsigned int*)g,
                                   (__attribute__((address_space(3))) unsigned int*)l,
                                   16, 0, 0);
}

// ------------- GEMM body (128x128 tile): C = A[4096][1024] @ Bt^T -------------
// MODE 0: bf16 row-major out; MODE 2: bf16 V-transposed out
// (vt[(b*16+h)*64+d][s], fusing the V-transpose into the V projection).
template <int MODE>
DEVINL void gemm_body(const unsigned short* __restrict__ A,
                      const unsigned short* __restrict__ Bt,
                      void* __restrict__ Cout) {
  constexpr int K = 1024, N = 1024;
  __shared__ alignas(16) unsigned short As[128 * 32];
  __shared__ alignas(16) unsigned short Bs[128 * 32];
  const int tid  = threadIdx.x;
  const int wave = tid >> 6, lane = tid & 63;
  const int quad = lane >> 4, l16 = lane & 15;
  const int mBase = blockIdx.y * 128, nBase = blockIdx.x * 128;
  const int wm = (wave >> 1) * 64, wn = (wave & 1) * 64;
  const int sr = lane >> 2;
  const int sc = (lane & 3) * 8;
  floatx4 acc[4][4] = {};

  for (int k0 = 0; k0 < K; k0 += 32) {
    __syncthreads();
#pragma unroll
    for (int j = 0; j < 2; ++j) {
      int row = wave * 32 + j * 16 + sr;
      load_lds16(A  + (size_t)(mBase + row) * K + k0 + sc, As + (wave * 32 + j * 16) * 32);
      load_lds16(Bt + (size_t)(nBase + row) * K + k0 + sc, Bs + (wave * 32 + j * 16) * 32);
    }
    __syncthreads();
    short8 af[4], bfr[4];
#pragma unroll
    for (int mt = 0; mt < 4; ++mt) af[mt]  = *(const short8*)&As[(wm + mt * 16 + l16) * 32 + quad * 8];
#pragma unroll
    for (int nt = 0; nt < 4; ++nt) bfr[nt] = *(const short8*)&Bs[(wn + nt * 16 + l16) * 32 + quad * 8];
#pragma unroll
    for (int mt = 0; mt < 4; ++mt)
#pragma unroll
      for (int nt = 0; nt < 4; ++nt)
        acc[mt][nt] = __builtin_amdgcn_mfma_f32_16x16x32_bf16(af[mt], bfr[nt], acc[mt][nt], 0, 0, 0);
  }

#pragma unroll
  for (int mt = 0; mt < 4; ++mt)
#pragma unroll
    for (int nt = 0; nt < 4; ++nt) {
      const int m = mBase + wm + mt * 16 + quad * 4;   // +r
      const int n = nBase + wn + nt * 16 + l16;
      if (MODE == 2) {
        const int bq = m >> 11, s = m & 2047;
        const int hh = n >> 6,  d = n & 63;
        unsigned short w4[4];
#pragma unroll
        for (int r = 0; r < 4; ++r) w4[r] = f2bf(acc[mt][nt][r]);
        *(uint2*)&((unsigned short*)Cout)[((size_t)((bq * 16 + hh) * 64 + d)) * S_LEN + s] =
            *(const uint2*)w4;
      } else {
#pragma unroll
        for (int r = 0; r < 4; ++r)
          ((unsigned short*)Cout)[(size_t)(m + r) * N + n] = f2bf(acc[mt][nt][r]);
      }
    }
}

__global__ __launch_bounds__(256) void gemm_qkv(const unsigned short* __restrict__ A0,
                                                const unsigned short* __restrict__ A1,
                                                const unsigned short* __restrict__ A2,
                                                const unsigned short* __restrict__ B0,
                                                const unsigned short* __restrict__ B1,
                                                const unsigned short* __restrict__ B2,
                                                unsigned short* __restrict__ C0,
                                                unsigned short* __restrict__ C1,
                                                unsigned short* __restrict__ C2) {
  const int z = blockIdx.z;
  if (z == 2)      gemm_body<2>(A2, B2, C2);   // V: write transposed vt directly
  else if (z == 1) gemm_body<0>(A1, B1, C1);
  else             gemm_body<0>(A0, B0, C0);
}

// ------------- output GEMM, 64x128 tile (512 blocks -> 2/CU overlap) -------------
__global__ __launch_bounds__(256) void gemm_out64(const unsigned short* __restrict__ A,
                                                  const unsigned short* __restrict__ Bt,
                                                  float* __restrict__ C) {
  constexpr int K = 1024, N = 1024;
  __shared__ alignas(16) unsigned short As[64 * 32];
  __shared__ alignas(16) unsigned short Bs[128 * 32];
  const int tid  = threadIdx.x;
  const int wave = tid >> 6, lane = tid & 63;
  const int quad = lane >> 4, l16 = lane & 15;
  const int mBase = blockIdx.y * 64, nBase = blockIdx.x * 128;
  const int wm = (wave >> 1) * 32, wn = (wave & 1) * 64;
  const int sr = lane >> 2;
  const int sc = (lane & 3) * 8;
  floatx4 acc[2][4] = {};

  for (int k0 = 0; k0 < K; k0 += 32) {
    __syncthreads();
    load_lds16(A + (size_t)(mBase + wave * 16 + sr) * K + k0 + sc, As + (wave * 16) * 32);
#pragma unroll
    for (int j = 0; j < 2; ++j) {
      int row = wave * 32 + j * 16 + sr;
      load_lds16(Bt + (size_t)(nBase + row) * K + k0 + sc, Bs + (wave * 32 + j * 16) * 32);
    }
    __syncthreads();
    short8 af[2], bfr[4];
#pragma unroll
    for (int mt = 0; mt < 2; ++mt) af[mt]  = *(const short8*)&As[(wm + mt * 16 + l16) * 32 + quad * 8];
#pragma unroll
    for (int nt = 0; nt < 4; ++nt) bfr[nt] = *(const short8*)&Bs[(wn + nt * 16 + l16) * 32 + quad * 8];
#pragma unroll
    for (int mt = 0; mt < 2; ++mt)
#pragma unroll
      for (int nt = 0; nt < 4; ++nt)
        acc[mt][nt] = __builtin_amdgcn_mfma_f32_16x16x32_bf16(af[mt], bfr[nt], acc[mt][nt], 0, 0, 0);
  }

#pragma unroll
  for (int mt = 0; mt < 2; ++mt)
#pragma unroll
    for (int nt = 0; nt < 4; ++nt)
#pragma unroll
      for (int r = 0; r < 4; ++r) {
        int m = mBase + wm + mt * 16 + quad * 4 + r;
        int n = nBase + wn + nt * 16 + l16;
        C[(size_t)m * N + n] = acc[mt][nt][r];
      }
}

// one KV-tile's QK + softmax + PV for all 4 q-subtiles (all indices static)
#define COMPUTE_TILE(KC0, KC1, VV, MASKED)                                        \
  {                                                                               \
    const bool masked_ = (MASKED);                                                \
    _Pragma("unroll")                                                             \
    for (int nt = 0; nt < 4; ++nt) {                                              \
      floatx4 sc = {};                                                            \
      sc = __builtin_amdgcn_mfma_f32_16x16x32_bf16(KC0, qB[nt][0], sc, 0, 0, 0);  \
      sc = __builtin_amdgcn_mfma_f32_16x16x32_bf16(KC1, qB[nt][1], sc, 0, 0, 0);  \
      const int qoff = nt * 16 + l16;                                             \
      sh4 pa;                                                                     \
      float acc = 0.f;                                                            \
      _Pragma("unroll")                                                           \
      for (int r = 0; r < 4; ++r) {                                               \
        float p = __builtin_amdgcn_exp2f(fmaf(sc[r], SM_C1, SM_C2));              \
        if (masked_ && (sbase + r > qoff)) p = 0.f;                               \
        acc += p;                                                                 \
        pa[r] = (short)f2bf_fast(p);                                              \
      }                                                                           \
      rs[nt] += acc;                                                              \
      _Pragma("unroll")                                                           \
      for (int dt = 0; dt < 4; ++dt)                                              \
        o[nt][dt] = MFMA16(pa, VV[dt], o[nt][dt]);                                \
    }                                                                             \
  }

// ------------- causal flash attention: PAIRED-TILE staging, dbuf pairs, register P ----
// S^T trick: QK as A=K,B=Q -> lane holds P[q=l16][s=quad*4+r] = A-operand layout of
// mfma 16x16x16 for PV -> P never leaves registers.
//
// R21 (this round): 2 KV-TILES PER BARRIER EVENT on the R16 base (45.4us).
// R16 paid 33 drain+barrier events/block, each adding 4-wave convergence +
// DMA-tail on top of ~650 cyc compute. Pair-buffers (2 tiles = 32 KB each,
// double-buffered): read ALL fragments of both tiles first (keeps the proven
// reads-before-issue pattern so hipcc inserts no alias-vmcnt before the
// reads), then issue the NEXT pair, then compute both tiles. Barrier events
// 33 -> 17; the next pair's DMA gets TWO compute phases (~1300 cyc) to
// complete. Epilogue = R19-proven 5 KB shared-atomicAdd accumulator (frees
// the 20 KB Ored so LDS = 65536 KVs + 5120 Acc + 4096 rsL = 74752 B -> still
// 2 blocks/CU). launch_bounds (256,2): fragment live range grows ~+32 VGPR;
// the 256-reg budget removes spill risk — occupancy is LDS-bound at 2
// blocks/CU regardless.
// R20 lesson: counted vmcnt at HIP source is DEFEATED — hipcc inserts its own
// vmcnt(0) before compiler-visible ds_reads that may alias outstanding DMA
// (133us). Stay with full-drain + __syncthreads (R13 contract).
// R19 lesson: q-split reverted (doubles staging, halves per-block compute).
// Rule #20: ALL loops touching o/qB/rs fully unrolled (one `#pragma unroll 1`
// epilogue cost R17/R18/R19 400MB-1GB scratch writes).
// R16: XCD remap — all 16 pair-blocks of a bh on one XCD, K/V L2-resident
// (FETCH 96->12 MB). R13: explicit vmcnt(0) before each in-loop barrier
// (barrier alone does not order vmcnt-tracked LDS-DMA — R12 raced).
// XOR swizzle chunk^=(row&7) both-sides. R9: pair (31-p, p) => 33 steps.
__global__ __launch_bounds__(256, 2) void attn_kernel(const unsigned short* __restrict__ Qp,
                                                      const unsigned short* __restrict__ Kp,
                                                      const unsigned short* __restrict__ Vtg,
                                                      unsigned short* __restrict__ ctx) {
  // ---- XCD-aware remap: keep all 16 pair-blocks of a bh on one XCD ----
  const int lin = (int)blockIdx.y * 16 + (int)blockIdx.x;   // dispatch linear id
  const int xcd = lin & 7;
  const int kk  = lin >> 3;                // 0..63
  const int bh  = ((kk >> 4) << 3) | xcd;  // 4 bh per XCD
  const int pairIdx = kk & 15;
  const int b  = bh >> 4, h = bh & 15;
  const int tid = threadIdx.x;
  const int w = tid >> 6, lane = tid & 63;
  const int quad = lane >> 4, l16 = lane & 15;

  // separate typed LDS (no aliasing). 65536 + 5120 + 4096 = 74752 B.
  __shared__ alignas(16) unsigned short KVs[4 * 8192];  // 2 pair-bufs x 2 tile slots
  __shared__ alignas(16) float Acc[4][16][20];          // atomic merge [dt][d16][q16 pad]
  __shared__ float rsL[4][4][16];                       // [wave][nt][q16]

  const unsigned short* Kbh = Kp  + (size_t)(b * S_LEN) * DM + h * DHEAD;
  const unsigned short* Vbh = Vtg + (size_t)(bh * DHEAD) * S_LEN;

  // ---- DMA staging geometry: wave w stages segment w*4KB of a 16KB tile ----
  int srow[4], scol[4];
#pragma unroll
  for (int j = 0; j < 4; ++j) {
    const int p = (w & 1) * 256 + j * 64 + lane;
    srow[j] = p >> 3;
    scol[j] = ((p & 7) ^ (srow[j] & 7)) * 8;
  }
  const bool stageK = (w < 2);

  // ---- swizzled read addresses (within a tile slot, shorts) ----
  const int swz = l16 & 7;
  const int kRow = (w * 16 + l16) * 64;
  const int kOff0 = kRow + ((0 + quad) ^ swz) * 8;       // K chunks quad, 4+quad
  const int kOff1 = kRow + ((4 + quad) ^ swz) * 8;
  int vOff[4];
#pragma unroll
  for (int dt = 0; dt < 4; ++dt) {
    const int ch = 2 * w + (quad >> 1);
    vOff[dt] = 4096 + (dt * 16 + l16) * 64 + (ch ^ swz) * 8 + (quad & 1) * 4;
  }

  // stage one 16KB tile (K rows kb..kb+63 + V^T cols kb..kb+63) into slot 0..3
  auto stageTile = [&](int kb, int slot) {
    unsigned short* dst = KVs + slot * 8192 + w * 2048;
#pragma unroll
    for (int j = 0; j < 4; ++j) {
      const unsigned short* src = stageK
          ? Kbh + (size_t)(kb + srow[j]) * DM + scol[j]
          : Vbh + (size_t)srow[j] * S_LEN + kb + scol[j];
      load_lds16(src, dst + j * 512);
    }
  };

#pragma unroll 1
  for (int half = 0; half < 2; ++half) {
    const int qt = half ? pairIdx : 31 - pairIdx;  // heavy tile first
    const int Q0 = qt * 64;
    const int nT = qt + 1;

    // Q fragments (B-operand: n=l16 -> q, k=quad*8+j -> d)
    short8 qB[4][2];
#pragma unroll
    for (int nt = 0; nt < 4; ++nt) {
      const size_t qr = ((size_t)(b * S_LEN + Q0 + nt * 16 + l16)) * DM + h * DHEAD + quad * 8;
      qB[nt][0] = *(const short8*)&Qp[qr];
      qB[nt][1] = *(const short8*)&Qp[qr + 32];
    }

    floatx4 o[4][4] = {};
    float rs[4] = {0.f, 0.f, 0.f, 0.f};

    // prologue: stage pair 0 (tiles 0 and 1) into pair-buffer 0
    stageTile(0, 0);
    if (nT > 1) stageTile(64, 1);
    int pairBuf = 0;

#pragma unroll 1
    for (int t = 0; t < nT; t += 2) {
      const bool two = (t + 1 < nT);
      // drain own DMA, then barrier publishes LDS writes (R13 contract; the
      // pair was issued a full 2-tile compute phase ago except the prologue).
      asm volatile("s_waitcnt vmcnt(0)" ::: "memory");
      __syncthreads();

      // read ALL fragments of both tiles FIRST (no ds_read after the DMA
      // issue below -> hipcc inserts no alias-drain before these reads)
      const unsigned short* bA = KVs + (pairBuf * 2 + 0) * 8192;
      short8 kA0 = *(const short8*)&bA[kOff0];
      short8 kA1 = *(const short8*)&bA[kOff1];
      sh4 vA[4];
#pragma unroll
      for (int dt = 0; dt < 4; ++dt) vA[dt] = *(const sh4*)&bA[vOff[dt]];

      short8 kB0 = kA0, kB1 = kA1;
      sh4 vB[4] = {vA[0], vA[1], vA[2], vA[3]};
      if (two) {
        const unsigned short* bB = KVs + (pairBuf * 2 + 1) * 8192;
        kB0 = *(const short8*)&bB[kOff0];
        kB1 = *(const short8*)&bB[kOff1];
#pragma unroll
        for (int dt = 0; dt < 4; ++dt) vB[dt] = *(const sh4*)&bB[vOff[dt]];
      }

      // THEN issue the next pair into the other pair-buffer; it overlaps the
      // 2-tile compute below and is drained at the next iteration's waitcnt.
      if (t + 2 < nT) {
        stageTile((t + 2) * 64, (pairBuf ^ 1) * 2 + 0);
        if (t + 3 < nT) stageTile((t + 3) * 64, (pairBuf ^ 1) * 2 + 1);
      }

      const int sbase = w * 16 + quad * 4;   // s - kb, + r

      COMPUTE_TILE(kA0, kA1, vA, (!two));            // t == nT-1 iff !two
      if (two) COMPUTE_TILE(kB0, kB1, vB, (t + 1 == nT - 1));

      pairBuf ^= 1;
    }

    // ---- epilogue: atomic merge of 4 wave-partials, normalize, write ctx ----
    // FULLY UNROLLED (rule #20).
#pragma unroll
    for (int nt = 0; nt < 4; ++nt) {
      rs[nt] += __shfl_xor(rs[nt], 16, 64);
      rs[nt] += __shfl_xor(rs[nt], 32, 64);
    }
    if (quad == 0) {
#pragma unroll
      for (int nt = 0; nt < 4; ++nt) rsL[w][nt][l16] = rs[nt];
    }

#pragma unroll
    for (int nt = 0; nt < 4; ++nt) {
      __syncthreads();                       // Acc free (prev round read done)
      {  // cooperative zero: 1280 floats / 256 threads = 5 each
        float* af = &Acc[0][0][0];
#pragma unroll
        for (int z = 0; z < 5; ++z) af[tid * 5 + z] = 0.f;
      }
      __syncthreads();
#pragma unroll
      for (int dt = 0; dt < 4; ++dt)
#pragma unroll
        for (int j = 0; j < 4; ++j)
          atomicAdd(&Acc[dt][l16][quad * 4 + j], o[nt][dt][j]);
      __syncthreads();
      // wave w outputs d-tile dt == w; lane -> (q16 = quad*4+j, d16 = l16)
#pragma unroll
      for (int j = 0; j < 4; ++j) {
        const int q16 = quad * 4 + j;
        const float l = rsL[0][nt][q16] + rsL[1][nt][q16] +
                        rsL[2][nt][q16] + rsL[3][nt][q16];
        const size_t row = (size_t)(b * S_LEN + Q0 + nt * 16 + q16);
        ctx[row * DM + h * DHEAD + w * 16 + l16] = f2bf(Acc[w][l16][q16] / l);
      }
    }
  }
}

extern "C" void kernel_launch(void* const* d_in, const int* in_sizes, int n_in,
                              void* d_out, int out_size, void* d_ws, size_t ws_size,
                              hipStream_t stream) {
  const float* Xq = (const float*)d_in[0];
  const float* Xk = (const float*)d_in[1];
  const float* Xv = (const float*)d_in[2];
  const float* Wq = (const float*)d_in[5];
  const float* Wk = (const float*)d_in[6];
  const float* Wv = (const float*)d_in[7];
  const float* Wo = (const float*)d_in[8];
  float* out = (float*)d_out;

  char* ws = (char*)d_ws;
  constexpr size_t XBYTES = (size_t)MROWS * DM * 2;  // 8 MiB
  constexpr size_t WBYTES = (size_t)DM * DM * 2;     // 2 MiB
  unsigned short* xq_bf = (unsigned short*)(ws);
  unsigned short* xk_bf = (unsigned short*)(ws + XBYTES);
  unsigned short* xv_bf = (unsigned short*)(ws + 2 * XBYTES);
  unsigned short* wqt   = (unsigned short*)(ws + 3 * XBYTES);
  unsigned short* wkt   = (unsigned short*)(ws + 3 * XBYTES + WBYTES);
  unsigned short* wvt   = (unsigned short*)(ws + 3 * XBYTES + 2 * WBYTES);
  unsigned short* wot   = (unsigned short*)(ws + 3 * XBYTES + 3 * WBYTES);
  unsigned short* qp    = (unsigned short*)(ws + 3 * XBYTES + 4 * WBYTES);
  unsigned short* kp    = (unsigned short*)(ws + 4 * XBYTES + 4 * WBYTES);
  unsigned short* vt    = (unsigned short*)(ws + 5 * XBYTES + 4 * WBYTES); // V^T, written by V-GEMM
  unsigned short* ctx   = xq_bf;  // dead after Q projection

  // fused prep: y=0..2 convert Xq/Xk/Xv; y=3 transpose the 4 weights
  prep_kernel<<<dim3(4096, 4), 256, 0, stream>>>(Xq, Xk, Xv, xq_bf, xk_bf, xv_bf,
                                                 Wq, Wk, Wv, Wo, wqt, wkt, wvt, wot);

  gemm_qkv<<<dim3(DM / 128, MROWS / 128, 3), 256, 0, stream>>>(
      xq_bf, xk_bf, xv_bf, wqt, wkt, wvt, qp, kp, vt);

  // paired causal schedule + XCD remap: block lin -> (bh with bh%8==lin%8, pair)
  // => all 16 pair-blocks of a bh on one XCD; uniform 33 steps each; 512 blocks.
  attn_kernel<<<dim3(16, BATCH * NHEAD), 256, 0, stream>>>(qp, kp, vt, ctx);

  gemm_out64<<<dim3(DM / 128, MROWS / 64), 256, 0, stream>>>(ctx, wot, out);
}

// Round 14
// 224.057 us; speedup vs baseline: 1.3912x; 1.3630x over previous
//
#include <hip/hip_runtime.h>

#define DEVINL __device__ __forceinline__

typedef __attribute__((ext_vector_type(8))) short short8;
typedef __attribute__((ext_vector_type(4))) short sh4;
typedef __attribute__((ext_vector_type(4))) float floatx4;

constexpr int S_LEN = 2048;
constexpr int DM    = 1024;
constexpr int NHEAD = 16;
constexpr int DHEAD = 64;
constexpr int BATCH = 2;
constexpr int MROWS = BATCH * S_LEN; // 4096
constexpr float LOG2E = 1.44269504f;
// fixed-max softmax: p = exp2(s_raw*0.125*LOG2E - 24*LOG2E); normalization cancels in O/l.
constexpr float SM_C1 = 0.125f * LOG2E;
constexpr float SM_C2 = -24.0f * LOG2E;

// 16x16x16 bf16 MFMA (A/B = 4 bf16 = 2 VGPR). No __has_builtin guard — amdgcn
// builtins are aux-target in the host pass (guard returns false there).
#define MFMA16(a, b, c) __builtin_amdgcn_mfma_f32_16x16x16bf16_1k(a, b, c, 0, 0, 0)

DEVINL unsigned short f2bf(float x) {  // RNE
  union { float f; unsigned u; } un; un.f = x;
  unsigned u = un.u;
  return (unsigned short)((u + 0x7fffu + ((u >> 16) & 1u)) >> 16);
}
DEVINL unsigned short f2bf_fast(float x) {  // round-half-up (x >= 0)
  union { float f; unsigned u; } un; un.f = x;
  return (unsigned short)((un.u + 0x8000u) >> 16);
}

// ---------------- prep: fp32->bf16 convert (3 tensors) + weight transpose (4) ----------------
__global__ __launch_bounds__(256) void prep_kernel(const float* __restrict__ s0,
                                                   const float* __restrict__ s1,
                                                   const float* __restrict__ s2,
                                                   unsigned short* __restrict__ d0,
                                                   unsigned short* __restrict__ d1,
                                                   unsigned short* __restrict__ d2,
                                                   const float* __restrict__ W0,
                                                   const float* __restrict__ W1,
                                                   const float* __restrict__ W2,
                                                   const float* __restrict__ W3,
                                                   unsigned short* __restrict__ T0,
                                                   unsigned short* __restrict__ T1,
                                                   unsigned short* __restrict__ T2,
                                                   unsigned short* __restrict__ T3) {
  __shared__ unsigned short tile[32][33];
  const int y = blockIdx.y;
  if (y < 3) {
    const float* s = y == 0 ? s0 : (y == 1 ? s1 : s2);
    unsigned short* d = y == 0 ? d0 : (y == 1 ? d1 : d2);
    int i = (blockIdx.x * 256 + threadIdx.x) * 4;
    float4 v = *(const float4*)(s + i);
    unsigned lo = (unsigned)f2bf(v.x) | ((unsigned)f2bf(v.y) << 16);
    unsigned hi = (unsigned)f2bf(v.z) | ((unsigned)f2bf(v.w) << 16);
    *(uint2*)(d + i) = make_uint2(lo, hi);
  } else {
    const int x = blockIdx.x;
    const int wsel = x >> 10, rem = x & 1023;
    const float* W = wsel == 0 ? W0 : (wsel == 1 ? W1 : (wsel == 2 ? W2 : W3));
    unsigned short* Wt = wsel == 0 ? T0 : (wsel == 1 ? T1 : (wsel == 2 ? T2 : T3));
    int t = threadIdx.x;
    int c = t & 31, r0 = t >> 5;
    int nB = (rem & 31) * 32, kB = (rem >> 5) * 32;
    for (int i = 0; i < 4; ++i) {
      int r = r0 + i * 8;
      tile[r][c] = f2bf(W[(size_t)(kB + r) * DM + nB + c]);
    }
    __syncthreads();
    for (int i = 0; i < 4; ++i) {
      int r = r0 + i * 8;
      Wt[(size_t)(nB + r) * DM + kB + c] = tile[c][r];
    }
  }
}

// ------------- async 16B global->LDS -------------
DEVINL void load_lds16(const unsigned short* g, unsigned short* l) {
  __builtin_amdgcn_global_load_lds((const __attribute__((address_space(1))) unsigned int*)g,
                                   (__attribute__((address_space(3))) unsigned int*)l,
                                   16, 0, 0);
}

// ------------- GEMM body (128x128 tile): C = A[4096][1024] @ Bt^T -------------
// MODE 0: bf16 row-major out; MODE 2: bf16 V-transposed out
// (vt[(b*16+h)*64+d][s], fusing the V-transpose into the V projection).
// by/bx are the (remapped) tile coordinates — R22: XCD swizzle applied by caller.
template <int MODE>
DEVINL void gemm_body(const unsigned short* __restrict__ A,
                      const unsigned short* __restrict__ Bt,
                      void* __restrict__ Cout, int by, int bx) {
  constexpr int K = 1024, N = 1024;
  __shared__ alignas(16) unsigned short As[128 * 32];
  __shared__ alignas(16) unsigned short Bs[128 * 32];
  const int tid  = threadIdx.x;
  const int wave = tid >> 6, lane = tid & 63;
  const int quad = lane >> 4, l16 = lane & 15;
  const int mBase = by * 128, nBase = bx * 128;
  const int wm = (wave >> 1) * 64, wn = (wave & 1) * 64;
  const int sr = lane >> 2;
  const int sc = (lane & 3) * 8;
  floatx4 acc[4][4] = {};

  for (int k0 = 0; k0 < K; k0 += 32) {
    __syncthreads();
#pragma unroll
    for (int j = 0; j < 2; ++j) {
      int row = wave * 32 + j * 16 + sr;
      load_lds16(A  + (size_t)(mBase + row) * K + k0 + sc, As + (wave * 32 + j * 16) * 32);
      load_lds16(Bt + (size_t)(nBase + row) * K + k0 + sc, Bs + (wave * 32 + j * 16) * 32);
    }
    __syncthreads();
    short8 af[4], bfr[4];
#pragma unroll
    for (int mt = 0; mt < 4; ++mt) af[mt]  = *(const short8*)&As[(wm + mt * 16 + l16) * 32 + quad * 8];
#pragma unroll
    for (int nt = 0; nt < 4; ++nt) bfr[nt] = *(const short8*)&Bs[(wn + nt * 16 + l16) * 32 + quad * 8];
#pragma unroll
    for (int mt = 0; mt < 4; ++mt)
#pragma unroll
      for (int nt = 0; nt < 4; ++nt)
        acc[mt][nt] = __builtin_amdgcn_mfma_f32_16x16x32_bf16(af[mt], bfr[nt], acc[mt][nt], 0, 0, 0);
  }

#pragma unroll
  for (int mt = 0; mt < 4; ++mt)
#pragma unroll
    for (int nt = 0; nt < 4; ++nt) {
      const int m = mBase + wm + mt * 16 + quad * 4;   // +r
      const int n = nBase + wn + nt * 16 + l16;
      if (MODE == 2) {
        const int bq = m >> 11, s = m & 2047;
        const int hh = n >> 6,  d = n & 63;
        unsigned short w4[4];
#pragma unroll
        for (int r = 0; r < 4; ++r) w4[r] = f2bf(acc[mt][nt][r]);
        *(uint2*)&((unsigned short*)Cout)[((size_t)((bq * 16 + hh) * 64 + d)) * S_LEN + s] =
            *(const uint2*)w4;
      } else {
#pragma unroll
        for (int r = 0; r < 4; ++r)
          ((unsigned short*)Cout)[(size_t)(m + r) * N + n] = f2bf(acc[mt][nt][r]);
      }
    }
}

// R22: XCD swizzle — per z-slice f = y*8+x in [0,256); xcd = f&7 (dispatch
// round-robin); each XCD owns 4 contiguous A-panels x all 8 B-panels:
// per-XCD working set 1 MB A + 2 MB B = 3 MB < 4 MB L2 (both L2-resident,
// vs default streaming all 8 MB of A through every XCD L2).
__global__ __launch_bounds__(256) void gemm_qkv(const unsigned short* __restrict__ A0,
                                                const unsigned short* __restrict__ A1,
                                                const unsigned short* __restrict__ A2,
                                                const unsigned short* __restrict__ B0,
                                                const unsigned short* __restrict__ B1,
                                                const unsigned short* __restrict__ B2,
                                                unsigned short* __restrict__ C0,
                                                unsigned short* __restrict__ C1,
                                                unsigned short* __restrict__ C2) {
  const int z = blockIdx.z;
  const int f = (int)blockIdx.y * 8 + (int)blockIdx.x;  // [0,256)
  const int xcd = f & 7, s = f >> 3;                    // s in [0,32)
  const int by = xcd * 4 + (s >> 3);                    // [0,32)
  const int bx = s & 7;                                 // [0,8)
  if (z == 2)      gemm_body<2>(A2, B2, C2, by, bx);   // V: write transposed vt directly
  else if (z == 1) gemm_body<0>(A1, B1, C1, by, bx);
  else             gemm_body<0>(A0, B0, C0, by, bx);
}

// ------------- output GEMM, 64x128 tile (512 blocks -> 2/CU overlap) -------------
__global__ __launch_bounds__(256) void gemm_out64(const unsigned short* __restrict__ A,
                                                  const unsigned short* __restrict__ Bt,
                                                  float* __restrict__ C) {
  constexpr int K = 1024, N = 1024;
  __shared__ alignas(16) unsigned short As[64 * 32];
  __shared__ alignas(16) unsigned short Bs[128 * 32];
  const int tid  = threadIdx.x;
  const int wave = tid >> 6, lane = tid & 63;
  const int quad = lane >> 4, l16 = lane & 15;
  // R22 XCD swizzle: f in [0,512); each XCD owns 8 contiguous A-panels (1 MB)
  // x all 8 B-panels (2 MB) -> 3 MB < 4 MB L2.
  const int f = (int)blockIdx.y * 8 + (int)blockIdx.x;
  const int xcd = f & 7, s = f >> 3;                    // s in [0,64)
  const int by = xcd * 8 + (s >> 3);                    // [0,64)
  const int bx = s & 7;                                 // [0,8)
  const int mBase = by * 64, nBase = bx * 128;
  const int wm = (wave >> 1) * 32, wn = (wave & 1) * 64;
  const int sr = lane >> 2;
  const int sc = (lane & 3) * 8;
  floatx4 acc[2][4] = {};

  for (int k0 = 0; k0 < K; k0 += 32) {
    __syncthreads();
    load_lds16(A + (size_t)(mBase + wave * 16 + sr) * K + k0 + sc, As + (wave * 16) * 32);
#pragma unroll
    for (int j = 0; j < 2; ++j) {
      int row = wave * 32 + j * 16 + sr;
      load_lds16(Bt + (size_t)(nBase + row) * K + k0 + sc, Bs + (wave * 32 + j * 16) * 32);
    }
    __syncthreads();
    short8 af[2], bfr[4];
#pragma unroll
    for (int mt = 0; mt < 2; ++mt) af[mt]  = *(const short8*)&As[(wm + mt * 16 + l16) * 32 + quad * 8];
#pragma unroll
    for (int nt = 0; nt < 4; ++nt) bfr[nt] = *(const short8*)&Bs[(wn + nt * 16 + l16) * 32 + quad * 8];
#pragma unroll
    for (int mt = 0; mt < 2; ++mt)
#pragma unroll
      for (int nt = 0; nt < 4; ++nt)
        acc[mt][nt] = __builtin_amdgcn_mfma_f32_16x16x32_bf16(af[mt], bfr[nt], acc[mt][nt], 0, 0, 0);
  }

#pragma unroll
  for (int mt = 0; mt < 2; ++mt)
#pragma unroll
    for (int nt = 0; nt < 4; ++nt)
#pragma unroll
      for (int r = 0; r < 4; ++r) {
        int m = mBase + wm + mt * 16 + quad * 4 + r;
        int n = nBase + wn + nt * 16 + l16;
        C[(size_t)m * N + n] = acc[mt][nt][r];
      }
}

// ------------- causal flash attention: DMA-staged double-buffered K/V, register P -------------
// R22: attn reverted VERBATIM to the R16 kernel (45.4us session best).
// R19-R21 lesson: all three "improved pipeline" attn variants (q-split /
// counted-vmcnt / paired-tile) collapsed to ~125us; the factor common to all
// three and absent here is the shared-atomicAdd(float) epilogue (likely CAS-
// loop lowering + cross-wave retry). This version's Ored store/load epilogue
// and 1-tile double-buffer with explicit vmcnt(0)+__syncthreads is the proven
// configuration:
//   * XCD remap: all 16 pair-blocks of a bh on one XCD -> K/V L2-resident
//     (FETCH 96 -> 12 MB measured).
//   * R13 contract: explicit s_waitcnt vmcnt(0) before each in-loop barrier
//     (barrier alone does NOT order vmcnt-tracked LDS-DMA — R12 raced).
//     Read fragments FIRST after the barrier, then issue next DMA.
//   * XOR swizzle chunk^=(row&7): DMA dest lane-linear, global source
//     pre-swizzled, reads apply the same XOR.
//   * pair (31-p, p) => uniform 33 steps; 512 blocks.
//   * rule #20: every loop touching o/qB/rs fully unrolled (runtime indexing
//     sent accumulators to scratch in R17/R18/R19: 400MB-1GB WRITE_SIZE).
__global__ __launch_bounds__(256, 3) void attn_kernel(const unsigned short* __restrict__ Qp,
                                                      const unsigned short* __restrict__ Kp,
                                                      const unsigned short* __restrict__ Vtg,
                                                      unsigned short* __restrict__ ctx) {
  // ---- XCD-aware remap: keep all 16 pair-blocks of a bh on one XCD ----
  const int lin = (int)blockIdx.y * 16 + (int)blockIdx.x;   // dispatch linear id
  const int xcd = lin & 7;
  const int kk  = lin >> 3;                // 0..63
  const int bh  = ((kk >> 4) << 3) | xcd;  // 4 bh per XCD
  const int pairIdx = kk & 15;
  const int b  = bh >> 4, h = bh & 15;
  const int tid = threadIdx.x;
  const int w = tid >> 6, lane = tid & 63;
  const int quad = lane >> 4, l16 = lane & 15;

  // [2 buffers][K 4096 shorts | V 4096 shorts]; tile rows are 64 shorts (128B, 8 chunks)
  __shared__ alignas(16) unsigned short KVs[2 * 8192];
  __shared__ float rsL[4][4][16];                        // [wave][nt][q16]
  __shared__ alignas(16) float Ored[4][4][16][20];       // padded: 80B rows -> 2-way max

  const unsigned short* Kbh = Kp  + (size_t)(b * S_LEN) * DM + h * DHEAD;
  const unsigned short* Vbh = Vtg + (size_t)(bh * DHEAD) * S_LEN;

  // ---- DMA staging geometry: wave w stages segment w*4KB of the 16KB tile pair ----
  int srow[4], scol[4];
#pragma unroll
  for (int j = 0; j < 4; ++j) {
    const int p = (w & 1) * 256 + j * 64 + lane;
    srow[j] = p >> 3;
    scol[j] = ((p & 7) ^ (srow[j] & 7)) * 8;
  }
  const bool stageK = (w < 2);

  // ---- swizzled read addresses (within a buffer, shorts) ----
  const int swz = l16 & 7;
  const int kRow = (w * 16 + l16) * 64;
  const int kOff0 = kRow + ((0 + quad) ^ swz) * 8;       // K chunks quad, 4+quad
  const int kOff1 = kRow + ((4 + quad) ^ swz) * 8;
  int vOff[4];
#pragma unroll
  for (int dt = 0; dt < 4; ++dt) {
    const int ch = 2 * w + (quad >> 1);
    vOff[dt] = 4096 + (dt * 16 + l16) * 64 + (ch ^ swz) * 8 + (quad & 1) * 4;
  }

  // issue DMA for tile 0 into buffer 0 (drained at the first in-loop waitcnt+barrier)
  {
    unsigned short* dst = KVs + w * 2048;
#pragma unroll
    for (int j = 0; j < 4; ++j) {
      const unsigned short* src = stageK
          ? Kbh + (size_t)srow[j] * DM + scol[j]
          : Vbh + (size_t)srow[j] * S_LEN + scol[j];
      load_lds16(src, dst + j * 512);
    }
  }

  int cur = 0;

#pragma unroll 1
  for (int half = 0; half < 2; ++half) {
    const int qt = half ? pairIdx : 31 - pairIdx;  // heavy tile first
    const int Q0 = qt * 64;
    const int nT = qt + 1;

    // Q fragments (B-operand: n=l16 -> q, k=quad*8+j -> d)
    short8 qB[4][2];
#pragma unroll
    for (int nt = 0; nt < 4; ++nt) {
      const size_t qr = ((size_t)(b * S_LEN + Q0 + nt * 16 + l16)) * DM + h * DHEAD + quad * 8;
      qB[nt][0] = *(const short8*)&Qp[qr];
      qB[nt][1] = *(const short8*)&Qp[qr + 32];
    }

    floatx4 o[4][4] = {};
    float rs[4] = {0.f, 0.f, 0.f, 0.f};

#pragma unroll 1
    for (int t = 0; t < nT; ++t) {
      // drain own DMA (issued a compute-phase ago -> ~no stall), then barrier
      // publishes the LDS writes to all waves. EXPLICIT because __syncthreads
      // alone does not order vmcnt-tracked LDS-DMA (R12 race).
      asm volatile("s_waitcnt vmcnt(0)" ::: "memory");
      __syncthreads();

      // fragments from LDS (swizzled) FIRST — nothing outstanding can stall
      // them; the may-alias DMA below cannot be hoisted above these reads.
      const unsigned short* buf = KVs + cur * 8192;
      short8 kc0 = *(const short8*)&buf[kOff0];
      short8 kc1 = *(const short8*)&buf[kOff1];
      sh4 vv[4];
#pragma unroll
      for (int dt = 0; dt < 4; ++dt) vv[dt] = *(const sh4*)&buf[vOff[dt]];

      // THEN issue DMA for the NEXT tile into the other buffer (tn=0 past the
      // end pre-warms tile 0 for the second q-tile); it overlaps this step's
      // compute and is drained at the next iteration's waitcnt.
      {
        const int tn = (t + 1 < nT) ? t + 1 : 0;
        const int kb = tn * 64;
        unsigned short* dst = KVs + (cur ^ 1) * 8192 + w * 2048;
#pragma unroll
        for (int j = 0; j < 4; ++j) {
          const unsigned short* src = stageK
              ? Kbh + (size_t)(kb + srow[j]) * DM + scol[j]
              : Vbh + (size_t)srow[j] * S_LEN + kb + scol[j];
          load_lds16(src, dst + j * 512);
        }
      }

      const bool masked = (t == nT - 1);
      const int sbase = w * 16 + quad * 4;   // s - kb, + r

#pragma unroll
      for (int nt = 0; nt < 4; ++nt) {
        floatx4 sc = {};
        sc = __builtin_amdgcn_mfma_f32_16x16x32_bf16(kc0, qB[nt][0], sc, 0, 0, 0);
        sc = __builtin_amdgcn_mfma_f32_16x16x32_bf16(kc1, qB[nt][1], sc, 0, 0, 0);
        const int qoff = nt * 16 + l16;      // q - Q0
        sh4 pa;
        float acc = 0.f;
#pragma unroll
        for (int r = 0; r < 4; ++r) {
          float p = __builtin_amdgcn_exp2f(fmaf(sc[r], SM_C1, SM_C2));
          if (masked && (sbase + r > qoff)) p = 0.f;
          acc += p;
          pa[r] = (short)f2bf_fast(p);
        }
        rs[nt] += acc;
#pragma unroll
        for (int dt = 0; dt < 4; ++dt)
          o[nt][dt] = MFMA16(pa, vv[dt], o[nt][dt]);
      }

      cur ^= 1;
    }

    // ---- epilogue: merge 4 wave-partials (additive), normalize, write ctx ----
    // (prewarm DMA for the next half stays in flight; it touches only KVs,
    // epilogue touches only Ored/rsL — drained at next half's first waitcnt)
#pragma unroll
    for (int nt = 0; nt < 4; ++nt) {
      rs[nt] += __shfl_xor(rs[nt], 16, 64);
      rs[nt] += __shfl_xor(rs[nt], 32, 64);
    }
    if (quad == 0) {
#pragma unroll
      for (int nt = 0; nt < 4; ++nt) rsL[w][nt][l16] = rs[nt];
    }

    for (int nt = 0; nt < 4; ++nt) {
      __syncthreads();
#pragma unroll
      for (int dt = 0; dt < 4; ++dt)
        *(floatx4*)&Ored[w][dt][l16][quad * 4] = o[nt][dt];
      __syncthreads();
      // wave w handles d-tile dt == w; lane -> (q = quad*4+j, d = w*16+l16)
      floatx4 acc = {};
#pragma unroll
      for (int w2 = 0; w2 < 4; ++w2) {
        floatx4 v = *(const floatx4*)&Ored[w2][w][l16][quad * 4];
#pragma unroll
        for (int j = 0; j < 4; ++j) acc[j] += v[j];
      }
#pragma unroll
      for (int j = 0; j < 4; ++j) {
        const int q16 = quad * 4 + j;
        float l = rsL[0][nt][q16] + rsL[1][nt][q16] + rsL[2][nt][q16] + rsL[3][nt][q16];
        const size_t row = (size_t)(b * S_LEN + Q0 + nt * 16 + q16);
        ctx[row * DM + h * DHEAD + w * 16 + l16] = f2bf(acc[j] / l);
      }
    }
  }
}

extern "C" void kernel_launch(void* const* d_in, const int* in_sizes, int n_in,
                              void* d_out, int out_size, void* d_ws, size_t ws_size,
                              hipStream_t stream) {
  const float* Xq = (const float*)d_in[0];
  const float* Xk = (const float*)d_in[1];
  const float* Xv = (const float*)d_in[2];
  const float* Wq = (const float*)d_in[5];
  const float* Wk = (const float*)d_in[6];
  const float* Wv = (const float*)d_in[7];
  const float* Wo = (const float*)d_in[8];
  float* out = (float*)d_out;

  char* ws = (char*)d_ws;
  constexpr size_t XBYTES = (size_t)MROWS * DM * 2;  // 8 MiB
  constexpr size_t WBYTES = (size_t)DM * DM * 2;     // 2 MiB
  unsigned short* xq_bf = (unsigned short*)(ws);
  unsigned short* xk_bf = (unsigned short*)(ws + XBYTES);
  unsigned short* xv_bf = (unsigned short*)(ws + 2 * XBYTES);
  unsigned short* wqt   = (unsigned short*)(ws + 3 * XBYTES);
  unsigned short* wkt   = (unsigned short*)(ws + 3 * XBYTES + WBYTES);
  unsigned short* wvt   = (unsigned short*)(ws + 3 * XBYTES + 2 * WBYTES);
  unsigned short* wot   = (unsigned short*)(ws + 3 * XBYTES + 3 * WBYTES);
  unsigned short* qp    = (unsigned short*)(ws + 3 * XBYTES + 4 * WBYTES);
  unsigned short* kp    = (unsigned short*)(ws + 4 * XBYTES + 4 * WBYTES);
  unsigned short* vt    = (unsigned short*)(ws + 5 * XBYTES + 4 * WBYTES); // V^T, written by V-GEMM
  unsigned short* ctx   = xq_bf;  // dead after Q projection

  // fused prep: y=0..2 convert Xq/Xk/Xv; y=3 transpose the 4 weights
  prep_kernel<<<dim3(4096, 4), 256, 0, stream>>>(Xq, Xk, Xv, xq_bf, xk_bf, xv_bf,
                                                 Wq, Wk, Wv, Wo, wqt, wkt, wvt, wot);

  gemm_qkv<<<dim3(DM / 128, MROWS / 128, 3), 256, 0, stream>>>(
      xq_bf, xk_bf, xv_bf, wqt, wkt, wvt, qp, kp, vt);

  // paired causal schedule + XCD remap: block lin -> (bh with bh%8==lin%8, pair)
  // => all 16 pair-blocks of a bh on one XCD; uniform 33 steps each; 512 blocks.
  attn_kernel<<<dim3(16, BATCH * NHEAD), 256, 0, stream>>>(qp, kp, vt, ctx);

  gemm_out64<<<dim3(DM / 128, MROWS / 64), 256, 0, stream>>>(ctx, wot, out);
}